// Round 7
// baseline (285.898 us; speedup 1.0000x reference)
//
#include <hip/hip_runtime.h>
#include <math.h>

#define N_PTS 8192
#define TPB 256
#define GRP 4          // rows per pipeline group
#define RPB (2 * GRP)  // 8 rows per block, two software-pipelined groups
// History: flat RPB=8 -> VGPR cliff (R1, -19us). RPB=1 -> 4x A-traffic, and
// cross-block pipelining is impossible (cohorts start/retire together, R4).
// This version pipelines INSIDE the block: A(g1) overlaps B-store-drain(g0),
// with g1's A-state reusing g0's dead registers.

// constants
#define C_LAMBDA   2.5f
#define C_REPEL    0.15f
#define C_EPS      0.1f
#define C_NORM_EPS 1e-8f
#define C_TAUW     0.3f
#define C_TWO_PI   6.28318530717958647692f
#define C_NEG_L_LOG2E (-3.60673760222240625f)   // -2.5 * log2(e)
#define C_Q_DELTA  1e-16f   // rsqrt guard: q==0 (diagonal) stays finite

typedef float vf4 __attribute__((ext_vector_type(4)));

__device__ __forceinline__ float fast_exp2(float x) {
#if __has_builtin(__builtin_amdgcn_exp2f)
    return __builtin_amdgcn_exp2f(x);
#else
    return exp2f(x);
#endif
}
__device__ __forceinline__ float fast_rsqrt(float x) {
#if __has_builtin(__builtin_amdgcn_rsqf)
    return __builtin_amdgcn_rsqf(x);
#else
    return rsqrtf(x);
#endif
}
__device__ __forceinline__ float fast_log2(float x) {
#if __has_builtin(__builtin_amdgcn_logf)
    return __builtin_amdgcn_logf(x);   // v_log_f32 = log2
#else
    return log2f(x);
#endif
}

__device__ __forceinline__ float wave_reduce_sum(float v) {
    #pragma unroll
    for (int off = 32; off > 0; off >>= 1)
        v += __shfl_down(v, off, 64);
    return v;
}

// pass-A inner body: one (row, j) pair.
// diagonal flows through (score=1 at j==i; repulsion self-term is exactly 0
// since dx=dy=0 and rsqrt stays finite via C_Q_DELTA); attention self-term is
// subtracted at finalize. trans ops calibrated ~13 cyc/wave64 -> minimized.
#define A_BODY(cur, TH, TA, CC, SS, AS, AX, AY, AT, RX, RY) do {           \
    float ad    = fabsf((TH) - (cur).x);                                   \
    float dth   = fminf(ad, C_TWO_PI - ad);                                \
    float t     = fmaf(fabsf((TA) - (cur).y), C_TAUW, dth);                \
    float score = fast_exp2(t * C_NEG_L_LOG2E);                            \
    (AS) += score;                                                         \
    (AX)  = fmaf(score, (cur).z, (AX));                                    \
    (AY)  = fmaf(score, (cur).w, (AY));                                    \
    (AT)  = fmaf(score, (cur).y, (AT));                                    \
    float d   = dth + C_EPS;                                               \
    float dx  = (CC) - (cur).z;                                            \
    float dy  = (SS) - (cur).w;                                            \
    float q   = fmaf(dx, dx, dy * dy);                                     \
    float d2  = d * d;                                                     \
    float inv = fast_rsqrt((q + C_Q_DELTA) * (d2 * d2));                   \
    (RX) = fmaf(inv, dx, (RX));                                            \
    (RY) = fmaf(inv, dy, (RY));                                            \
} while (0)

// pass-B: one normalized attention value (theta_j, tau_j) vs uniform row (thb, tab, l2b)
#define B_VAL(THJ, TAJ, THB, TAB, L2B, V) do {                             \
    float ad  = fabsf((THB) - (THJ));                                      \
    float dth = fminf(ad, C_TWO_PI - ad);                                  \
    float t   = fmaf(fabsf((TAB) - (TAJ)), C_TAUW, dth);                   \
    (V) = fast_exp2(fmaf(t, C_NEG_L_LOG2E, (L2B)));                        \
} while (0)

// Pack j-stream: pk[j] = {theta, tau, cos, sin}; pk2[j] = {theta, tau}
__global__ void pack_kernel(const float* __restrict__ theta,
                            const float* __restrict__ tau,
                            float4* __restrict__ pk,
                            float2* __restrict__ pk2) {
    int i = blockIdx.x * blockDim.x + threadIdx.x;
    float t = theta[i];
    float u = tau[i];
    pk[i]  = make_float4(t, u, cosf(t), sinf(t));
    pk2[i] = make_float2(t, u);
}

__global__ __launch_bounds__(TPB) void fused_kernel(
    const float4* __restrict__ pk,
    const float4* __restrict__ pq,   // (float4*)pk2: {th(2m),ta(2m),th(2m+1),ta(2m+1)}
    float* __restrict__ out)         // [theta_out(N) | tau_out(N) | attn(N*N)]
{
    const int tid  = threadIdx.x;
    const int row0 = blockIdx.x * RPB;
    const int wave = tid >> 6;
    const int lane = tid & 63;

    __shared__ float red[GRP][6][TPB / 64];
    __shared__ float l2sA[GRP];   // log2(invsum) for group 0 rows
    __shared__ float l2sB[GRP];   // log2(invsum) for group 1 rows

    float* __restrict__ attn = out + 2 * N_PTS;

    // ================= stage 1: pass A, group 0 (rows row0..row0+3) =========
    float th[GRP], ta[GRP], cc[GRP], ss[GRP];
    float aS[GRP], aX[GRP], aY[GRP], aT[GRP], rX[GRP], rY[GRP];
    #pragma unroll
    for (int r = 0; r < GRP; ++r) {
        float4 p = pk[row0 + r];
        th[r] = p.x; ta[r] = p.y; cc[r] = p.z; ss[r] = p.w;
        aS[r] = 0.f; aX[r] = 0.f; aY[r] = 0.f;
        aT[r] = 0.f; rX[r] = 0.f; rY[r] = 0.f;
    }

    #pragma unroll 4
    for (int k = 0; k < N_PTS / TPB; ++k) {
        float4 cur = pk[tid + k * TPB];
        #pragma unroll
        for (int r = 0; r < GRP; ++r)
            A_BODY(cur, th[r], ta[r], cc[r], ss[r],
                   aS[r], aX[r], aY[r], aT[r], rX[r], rY[r]);
    }

    #pragma unroll
    for (int r = 0; r < GRP; ++r) {
        float v0 = wave_reduce_sum(aS[r]);
        float v1 = wave_reduce_sum(aX[r]);
        float v2 = wave_reduce_sum(aY[r]);
        float v3 = wave_reduce_sum(aT[r]);
        float v4 = wave_reduce_sum(rX[r]);
        float v5 = wave_reduce_sum(rY[r]);
        if (lane == 0) {
            red[r][0][wave] = v0; red[r][1][wave] = v1; red[r][2][wave] = v2;
            red[r][3][wave] = v3; red[r][4][wave] = v4; red[r][5][wave] = v5;
        }
    }
    __syncthreads();

    if (tid < GRP) {
        const int r = tid;
        float s = 0.f, x = 0.f, y = 0.f, t = 0.f, rx = 0.f, ry = 0.f;
        #pragma unroll
        for (int w = 0; w < TPB / 64; ++w) {
            s  += red[r][0][w]; x  += red[r][1][w]; y  += red[r][2][w];
            t  += red[r][3][w]; rx += red[r][4][w]; ry += red[r][5][w];
        }
        float4 p = pk[row0 + r];
        s -= 1.0f;                // remove j==i self-contribution (score==1)
        x -= p.z;  y -= p.w;  t -= p.y;
        float invr = 1.0f / s;
        float fx = fmaf(x, invr, C_REPEL * rx);
        float fy = fmaf(y, invr, C_REPEL * ry);
        out[row0 + r]         = atan2f(fy, fx);
        out[N_PTS + row0 + r] = t * invr;
        l2sA[r] = fast_log2(invr);
    }
    __syncthreads();

    // ====== stage 2: pass A group 1 (rows row0+4..row0+7), reusing g0's =====
    // ====== registers, interleaved with pass B stores for group 0.      =====
    #pragma unroll
    for (int r = 0; r < GRP; ++r) {
        float4 p = pk[row0 + GRP + r];
        th[r] = p.x; ta[r] = p.y; cc[r] = p.z; ss[r] = p.w;
        aS[r] = 0.f; aX[r] = 0.f; aY[r] = 0.f;
        aT[r] = 0.f; rX[r] = 0.f; rY[r] = 0.f;
    }

    // 32 A k-iters == 4 B rows x 8 quad-chunks: interleave 1:1. B is r-outer
    // (one active 32KB write region per block, sequential in kk).
    #pragma unroll 1
    for (int rb = 0; rb < GRP; ++rb) {
        float4 pr  = pk[row0 + rb];      // wave-uniform row constants for B
        float  thb = pr.x, tab = pr.y;
        float  l2b = l2sA[rb];
        float* __restrict__ rowp = attn + (size_t)(row0 + rb) * N_PTS;
        #pragma unroll 1
        for (int kk = 0; kk < N_PTS / (TPB * 4); ++kk) {
            // --- A body for group 1, k = rb*8 + kk ---
            float4 cur = pk[tid + (rb * (N_PTS / (TPB * 4)) + kk) * TPB];
            #pragma unroll
            for (int r = 0; r < GRP; ++r)
                A_BODY(cur, th[r], ta[r], cc[r], ss[r],
                       aS[r], aX[r], aY[r], aT[r], rX[r], rY[r]);
            // --- B chunk for group-0 row rb: 4 j's, one float4 store ---
            const int base = tid + kk * TPB;
            float4 f1 = pq[2 * base];
            float4 f2 = pq[2 * base + 1];
            float v0, v1, v2, v3;
            B_VAL(f1.x, f1.y, thb, tab, l2b, v0);
            B_VAL(f1.z, f1.w, thb, tab, l2b, v1);
            B_VAL(f2.x, f2.y, thb, tab, l2b, v2);
            B_VAL(f2.z, f2.w, thb, tab, l2b, v3);
            vf4 o = {v0, v1, v2, v3};
            *(vf4*)(rowp + 4 * base) = o;
        }
    }

    #pragma unroll
    for (int r = 0; r < GRP; ++r) {
        float v0 = wave_reduce_sum(aS[r]);
        float v1 = wave_reduce_sum(aX[r]);
        float v2 = wave_reduce_sum(aY[r]);
        float v3 = wave_reduce_sum(aT[r]);
        float v4 = wave_reduce_sum(rX[r]);
        float v5 = wave_reduce_sum(rY[r]);
        if (lane == 0) {
            red[r][0][wave] = v0; red[r][1][wave] = v1; red[r][2][wave] = v2;
            red[r][3][wave] = v3; red[r][4][wave] = v4; red[r][5][wave] = v5;
        }
    }
    __syncthreads();

    if (tid < GRP) {
        const int r = tid;
        float s = 0.f, x = 0.f, y = 0.f, t = 0.f, rx = 0.f, ry = 0.f;
        #pragma unroll
        for (int w = 0; w < TPB / 64; ++w) {
            s  += red[r][0][w]; x  += red[r][1][w]; y  += red[r][2][w];
            t  += red[r][3][w]; rx += red[r][4][w]; ry += red[r][5][w];
        }
        float4 p = pk[row0 + GRP + r];
        s -= 1.0f;
        x -= p.z;  y -= p.w;  t -= p.y;
        float invr = 1.0f / s;
        float fx = fmaf(x, invr, C_REPEL * rx);
        float fy = fmaf(y, invr, C_REPEL * ry);
        out[row0 + GRP + r]         = atan2f(fy, fx);
        out[N_PTS + row0 + GRP + r] = t * invr;
        l2sB[r] = fast_log2(invr);
    }
    __syncthreads();

    // ================= stage 3: pass B, group 1 ==============================
    #pragma unroll 1
    for (int rb = 0; rb < GRP; ++rb) {
        float4 pr  = pk[row0 + GRP + rb];
        float  thb = pr.x, tab = pr.y;
        float  l2b = l2sB[rb];
        float* __restrict__ rowp = attn + (size_t)(row0 + GRP + rb) * N_PTS;
        #pragma unroll 2
        for (int kk = 0; kk < N_PTS / (TPB * 4); ++kk) {
            const int base = tid + kk * TPB;
            float4 f1 = pq[2 * base];
            float4 f2 = pq[2 * base + 1];
            float v0, v1, v2, v3;
            B_VAL(f1.x, f1.y, thb, tab, l2b, v0);
            B_VAL(f1.z, f1.w, thb, tab, l2b, v1);
            B_VAL(f2.x, f2.y, thb, tab, l2b, v2);
            B_VAL(f2.z, f2.w, thb, tab, l2b, v3);
            vf4 o = {v0, v1, v2, v3};
            *(vf4*)(rowp + 4 * base) = o;
        }
    }

    // diagonal: overwrite attn[i][i] = 0 after all row stores (workgroup fence)
    __syncthreads();
    if (tid < RPB) {
        const int i = row0 + tid;
        attn[(size_t)i * N_PTS + i] = 0.0f;
    }
}

extern "C" void kernel_launch(void* const* d_in, const int* in_sizes, int n_in,
                              void* d_out, int out_size, void* d_ws, size_t ws_size,
                              hipStream_t stream) {
    const float* theta = (const float*)d_in[0];
    const float* tau   = (const float*)d_in[1];

    float4* pk  = (float4*)d_ws;                          // 128 KB
    float2* pk2 = (float2*)((char*)d_ws + 128 * 1024);    //  64 KB
    float*  out = (float*)d_out;

    pack_kernel<<<N_PTS / 256, 256, 0, stream>>>(theta, tau, pk, pk2);
    fused_kernel<<<N_PTS / RPB, TPB, 0, stream>>>(pk, (const float4*)pk2, out);
}

// Round 8
// 278.130 us; speedup vs baseline: 1.0279x; 1.0279x over previous
//
#include <hip/hip_runtime.h>
#include <math.h>

#define N_PTS 8192
#define TPB 256
#define RPB 4
// RPB=4 verified optimum: RPB=8 flat -> VGPR cliff (R1, -19us); RPB=1 -> 4x
// A-traffic (R4, -8.8us); intra-block A/B interleave -> -11us (R7): blocks
// already pipeline naturally across cohorts, the store stream itself is slow.
// R8 theory: in-order vmcnt means pq loads inside the B loop force earlier
// attn stores to COMPLETE (store round-trip ~100s of cycles per iter).
// Fix: preload each thread's pq working set (64 floats) into registers, so
// the store loop has zero VMEM reads -> stores stream fire-and-forget.

// constants
#define C_LAMBDA   2.5f
#define C_REPEL    0.15f
#define C_EPS      0.1f
#define C_NORM_EPS 1e-8f
#define C_TAUW     0.3f
#define C_TWO_PI   6.28318530717958647692f
#define C_NEG_L_LOG2E (-3.60673760222240625f)   // -2.5 * log2(e)
#define C_Q_DELTA  1e-16f   // rsqrt guard: q==0 (diagonal) stays finite

#define BCHUNK (N_PTS / (TPB * 4))   // 8 quad-chunks per row in pass B

typedef float vf4 __attribute__((ext_vector_type(4)));

__device__ __forceinline__ float fast_exp2(float x) {
#if __has_builtin(__builtin_amdgcn_exp2f)
    return __builtin_amdgcn_exp2f(x);
#else
    return exp2f(x);
#endif
}
__device__ __forceinline__ float fast_rsqrt(float x) {
#if __has_builtin(__builtin_amdgcn_rsqf)
    return __builtin_amdgcn_rsqf(x);
#else
    return rsqrtf(x);
#endif
}
__device__ __forceinline__ float fast_log2(float x) {
#if __has_builtin(__builtin_amdgcn_logf)
    return __builtin_amdgcn_logf(x);   // v_log_f32 = log2
#else
    return log2f(x);
#endif
}

__device__ __forceinline__ float wave_reduce_sum(float v) {
    #pragma unroll
    for (int off = 32; off > 0; off >>= 1)
        v += __shfl_down(v, off, 64);
    return v;
}

// pass-B: one normalized attention value (theta_j, tau_j) vs uniform row (thb, tab, l2b)
#define B_VAL(THJ, TAJ, THB, TAB, L2B, V) do {                             \
    float ad  = fabsf((THB) - (THJ));                                      \
    float dth = fminf(ad, C_TWO_PI - ad);                                  \
    float t   = fmaf(fabsf((TAB) - (TAJ)), C_TAUW, dth);                   \
    (V) = fast_exp2(fmaf(t, C_NEG_L_LOG2E, (L2B)));                        \
} while (0)

// Pack j-stream: pk[j] = {theta, tau, cos, sin}; pk2[j] = {theta, tau}
__global__ void pack_kernel(const float* __restrict__ theta,
                            const float* __restrict__ tau,
                            float4* __restrict__ pk,
                            float2* __restrict__ pk2) {
    int i = blockIdx.x * blockDim.x + threadIdx.x;
    float t = theta[i];
    float u = tau[i];
    pk[i]  = make_float4(t, u, cosf(t), sinf(t));
    pk2[i] = make_float2(t, u);
}

// Fused: pass A = per-row reductions (theta_out, tau_out, invsum);
//        pass B = normalized attn row writeback (register-cached pq).
__global__ __launch_bounds__(TPB) void fused_kernel(
    const float4* __restrict__ pk,
    const float4* __restrict__ pq,   // (float4*)pk2: {th(2m),ta(2m),th(2m+1),ta(2m+1)}
    float* __restrict__ out)         // [theta_out(N) | tau_out(N) | attn(N*N)]
{
    const int tid  = threadIdx.x;
    const int row0 = blockIdx.x * RPB;

    float th_i[RPB], ta_i[RPB], c_i[RPB], s_i[RPB];
    #pragma unroll
    for (int r = 0; r < RPB; ++r) {
        float4 p = pk[row0 + r];
        th_i[r] = p.x; ta_i[r] = p.y; c_i[r] = p.z; s_i[r] = p.w;
    }

    float a_sum[RPB], a_x[RPB], a_y[RPB], a_t[RPB], rp_x[RPB], rp_y[RPB];
    #pragma unroll
    for (int r = 0; r < RPB; ++r) {
        a_sum[r] = 0.f; a_x[r] = 0.f; a_y[r] = 0.f;
        a_t[r] = 0.f; rp_x[r] = 0.f; rp_y[r] = 0.f;
    }

    // ---- pass A: j-sweep; compiler-scheduled loads ----
    // diagonal flows through (score=1 at j==i; repulsion self-term is exactly
    // 0 since dx=dy=0 and rsqrt stays finite via C_Q_DELTA); attention
    // self-contribution is subtracted in the finalize step.
    #pragma unroll 4
    for (int k = 0; k < N_PTS / TPB; ++k) {
        float4 cur = pk[tid + k * TPB];
        #pragma unroll
        for (int r = 0; r < RPB; ++r) {
            float ad    = fabsf(th_i[r] - cur.x);
            float dth   = fminf(ad, C_TWO_PI - ad);
            float t     = fmaf(fabsf(ta_i[r] - cur.y), C_TAUW, dth);
            float score = fast_exp2(t * C_NEG_L_LOG2E);
            a_sum[r] += score;
            a_x[r]   = fmaf(score, cur.z, a_x[r]);
            a_y[r]   = fmaf(score, cur.w, a_y[r]);
            a_t[r]   = fmaf(score, cur.y, a_t[r]);

            float d   = dth + C_EPS;
            float dx  = c_i[r] - cur.z;
            float dy  = s_i[r] - cur.w;
            float q   = fmaf(dx, dx, dy * dy);
            float d2  = d * d;
            // 1/(d^2*(sqrt(q)+1e-8)) ~= rsqrt((q+delta)*d^4): one trans op
            // (trans ops calibrated ~12.5 cyc/wave64 on gfx950 -> minimize).
            float inv = fast_rsqrt((q + C_Q_DELTA) * (d2 * d2));
            rp_x[r] = fmaf(inv, dx, rp_x[r]);
            rp_y[r] = fmaf(inv, dy, rp_y[r]);
        }
    }

    __shared__ float red[RPB][6][TPB / 64];
    __shared__ float l2s[RPB];
    const int wave = tid >> 6;
    const int lane = tid & 63;
    #pragma unroll
    for (int r = 0; r < RPB; ++r) {
        float v0 = wave_reduce_sum(a_sum[r]);
        float v1 = wave_reduce_sum(a_x[r]);
        float v2 = wave_reduce_sum(a_y[r]);
        float v3 = wave_reduce_sum(a_t[r]);
        float v4 = wave_reduce_sum(rp_x[r]);
        float v5 = wave_reduce_sum(rp_y[r]);
        if (lane == 0) {
            red[r][0][wave] = v0; red[r][1][wave] = v1; red[r][2][wave] = v2;
            red[r][3][wave] = v3; red[r][4][wave] = v4; red[r][5][wave] = v5;
        }
    }
    __syncthreads();

    if (tid < RPB) {
        const int r = tid;
        float s = 0.f, x = 0.f, y = 0.f, t = 0.f, rx = 0.f, ry = 0.f;
        #pragma unroll
        for (int w = 0; w < TPB / 64; ++w) {
            s  += red[r][0][w]; x  += red[r][1][w]; y  += red[r][2][w];
            t  += red[r][3][w]; rx += red[r][4][w]; ry += red[r][5][w];
        }
        // subtract the j==i attention self-contribution (score == 1)
        float4 p = pk[row0 + r];
        s -= 1.0f;
        x -= p.z;
        y -= p.w;
        t -= p.y;
        float invr = 1.0f / s;
        float fx = fmaf(x, invr, C_REPEL * rx);
        float fy = fmaf(y, invr, C_REPEL * ry);
        out[row0 + r]         = atan2f(fy, fx);   // theta_out
        out[N_PTS + row0 + r] = t * invr;         // tau_out
        l2s[r] = fast_log2(invr);                 // fold normalization into exp2
    }
    __syncthreads();

    // ---- pass B ----
    // Preload this thread's entire pq working set into registers (16 float4
    // = 64 VGPR) so the store loop below contains NO VMEM reads. Rationale:
    // vmcnt is in-order across loads AND stores; a pq load inside the loop
    // would make its s_waitcnt drain all earlier attn stores (store
    // round-trip latency every iteration). With zero reads, stores are
    // fire-and-forget and pace at HBM drain rate like a fillBuffer.
    float l2r[RPB];
    #pragma unroll
    for (int r = 0; r < RPB; ++r) l2r[r] = l2s[r];

    float4 q1[BCHUNK], q2[BCHUNK];
    #pragma unroll
    for (int kk = 0; kk < BCHUNK; ++kk) {
        const int base = tid + kk * TPB;
        q1[kk] = pq[2 * base];
        q2[kk] = pq[2 * base + 1];
    }

    float* __restrict__ attn = out + 2 * N_PTS;

    #pragma unroll
    for (int kk = 0; kk < BCHUNK; ++kk) {
        const int base = tid + kk * TPB;      // pair-of-float2 quad index
        const float4 f1 = q1[kk];             // j0, j0+1
        const float4 f2 = q2[kk];             // j0+2, j0+3
        const int j0 = 4 * base;
        #pragma unroll
        for (int r = 0; r < RPB; ++r) {
            float v0, v1, v2, v3;
            B_VAL(f1.x, f1.y, th_i[r], ta_i[r], l2r[r], v0);
            B_VAL(f1.z, f1.w, th_i[r], ta_i[r], l2r[r], v1);
            B_VAL(f2.x, f2.y, th_i[r], ta_i[r], l2r[r], v2);
            B_VAL(f2.z, f2.w, th_i[r], ta_i[r], l2r[r], v3);
            vf4 o = {v0, v1, v2, v3};
            *(vf4*)(attn + (size_t)(row0 + r) * N_PTS + j0) = o;
        }
    }

    // diagonal: overwrite attn[i][i] = 0 after all row stores (workgroup fence)
    __syncthreads();
    if (tid < RPB) {
        const int i = row0 + tid;
        attn[(size_t)i * N_PTS + i] = 0.0f;
    }
}

extern "C" void kernel_launch(void* const* d_in, const int* in_sizes, int n_in,
                              void* d_out, int out_size, void* d_ws, size_t ws_size,
                              hipStream_t stream) {
    const float* theta = (const float*)d_in[0];
    const float* tau   = (const float*)d_in[1];

    float4* pk  = (float4*)d_ws;                          // 128 KB
    float2* pk2 = (float2*)((char*)d_ws + 128 * 1024);    //  64 KB
    float*  out = (float*)d_out;

    pack_kernel<<<N_PTS / 256, 256, 0, stream>>>(theta, tau, pk, pk2);
    fused_kernel<<<N_PTS / RPB, TPB, 0, stream>>>(pk, (const float4*)pk2, out);
}